// Round 10
// baseline (261.525 us; speedup 1.0000x reference)
//
#include <hip/hip_runtime.h>
#include <hip/hip_bf16.h>

typedef __attribute__((ext_vector_type(4))) float f32x4;
typedef __attribute__((ext_vector_type(8))) short bf16x8;

// fp32 -> bf16 bits, round-to-nearest-even
__device__ __forceinline__ unsigned short f2bf(float f) {
  unsigned int u = __builtin_bit_cast(unsigned int, f);
  u += 0x7FFFu + ((u >> 16) & 1u);
  return (unsigned short)(u >> 16);
}

// async 16B global -> LDS (wave-uniform LDS base + lane*16 hardware layout)
__device__ __forceinline__ void async_ld16(const void* g, void* l) {
  __builtin_amdgcn_global_load_lds(
      (__attribute__((address_space(1))) void*)g,
      (__attribute__((address_space(3))) void*)l, 16, 0, 0);
}

// ---------------------------------------------------------------------------
// Weight packing: fragment-order bf16 (same lane-mapping serves A-op & B-op).
// Apack[chunk][t][lane][j] = Acat[chunk*32 + (lane>>4)*8 + j][t*16 + (lane&15)]
// Bpack[kc][nt][lane][j]   = SCALE * Bcat[kc*32 + (lane>>4)*8 + j][nt*16 + (lane&15)]
// ---------------------------------------------------------------------------
__global__ __launch_bounds__(256) void pack_AB(
    const float* __restrict__ Af, const float* __restrict__ Am,
    const float* __restrict__ As, const float* __restrict__ Bf,
    const float* __restrict__ Bm, const float* __restrict__ Bs,
    short* __restrict__ Apack, short* __restrict__ Bpack)
{
  unsigned idx = blockIdx.x * 256u + threadIdx.x;     // < 786432
  if (idx < 393216u) {
    unsigned j = idx & 7u, lane = (idx >> 3) & 63u, rest = idx >> 9;
    unsigned t = rest % 6u, chunk = rest / 6u;
    unsigned k = chunk * 32u + ((lane >> 4) << 3) + j;
    unsigned c = t * 16u + (lane & 15u);
    float v;
    if (c < 32u)      v = Af[k * 32u + c];
    else if (c < 64u) v = Am[k * 32u + (c - 32u)];
    else              v = As[k * 32u + (c - 64u)];
    Apack[idx] = (short)f2bf(v);
  } else {
    unsigned i2 = idx - 393216u;
    unsigned j = i2 & 7u, lane = (i2 >> 3) & 63u, rest = i2 >> 9;
    unsigned nt = rest & 255u, kc = rest >> 8;
    unsigned k = kc * 32u + ((lane >> 4) << 3) + j;
    unsigned n = nt * 16u + (lane & 15u);
    float v;
    if (k < 32u)      v = Bf[k * 4096u + n];
    else if (k < 64u) v = Bm[(k - 32u) * 4096u + n];
    else              v = Bs[(k - 64u) * 4096u + n];
    Bpack[i2] = (short)f2bf(v * 0.03125f);            // fold SCALE = 1/32
  }
}

// ---------------------------------------------------------------------------
// Stage 1: fp32 h-partials = x-half @ Apack-half. Grid 2048 = 1024 row-tiles
// x 2 K-halves -> ~6 independent block pipelines/CU. 16 steps of K=128
// (8 KB staged/step), 2 buffers, r7-proven counted wait: newest-2 = the two
// DMAs just issued (vmcnt(2)), so stage(st) AND this step's A-loads drain in
// one shadow. A-fragments hoisted above the wait (sched_barrier fenced).
// ---------------------------------------------------------------------------
__global__ __launch_bounds__(256, 4) void lora_stage1(
    const float* __restrict__ x, const short* __restrict__ Apack,
    float* __restrict__ hg)
{
  const int bid  = blockIdx.x;
  const int tile = bid >> 1;             // 16-row tile
  const int half = bid & 1;              // K half: k in [half*2048, +2048)
  const int tid = threadIdx.x;
  const int w = tid >> 6, l = tid & 63;
  const int lm = l & 15, lk = l >> 4;
  const size_t rowbase = (size_t)tile * 16;

  __shared__ __align__(16) float smem[6400];   // 25.6 KB: 2x8KB staging -> hp

  f32x4 acc[6];
#pragma unroll
  for (int t = 0; t < 6; ++t) acc[t] = (f32x4){0.f, 0.f, 0.f, 0.f};

  // stage step s (512 B/row x 16 rows) into buffer b. Wave w: rows w*4..+4,
  // 2 DMA ops (each 1 KB = 2 rows). Per-lane SOURCE swizzle blk^(row&7);
  // LDS dest linear (wave-uniform base, HW lane*16 layout).
  auto stage = [&](int s, int b) {
    float* base = smem + b * 2048;
    const float* gx = x + rowbase * 4096 + half * 2048 + s * 128;
#pragma unroll
    for (int i = 0; i < 2; ++i) {
      int rp = w * 4 + i * 2;            // first row of this op's pair
      int row = rp + (l >> 5);
      int blk = (l & 31) ^ (row & 7);    // 16B-block within the row chunk
      async_ld16(gx + (size_t)row * 4096 + blk * 4, base + rp * 128);
    }
  };

  auto consume = [&](int st, const bf16x8* av) {
    const float* rowp = smem + (st & 1) * 2048 + lm * 128;
    const int sw = lm & 7;
    const int b0 = w * 8 + lk * 2;       // wave w owns ksub w of this step
    f32x4 xa = *(const f32x4*)(rowp + ((b0 ^ sw) << 2));
    f32x4 xb = *(const f32x4*)(rowp + (((b0 + 1) ^ sw) << 2));
    bf16x8 xf;
    xf[0] = (short)f2bf(xa[0]); xf[1] = (short)f2bf(xa[1]);
    xf[2] = (short)f2bf(xa[2]); xf[3] = (short)f2bf(xa[3]);
    xf[4] = (short)f2bf(xb[0]); xf[5] = (short)f2bf(xb[1]);
    xf[6] = (short)f2bf(xb[2]); xf[7] = (short)f2bf(xb[3]);
#pragma unroll
    for (int t = 0; t < 6; ++t)
      acc[t] = __builtin_amdgcn_mfma_f32_16x16x32_bf16(xf, av[t], acc[t], 0, 0, 0);
  };

  stage(0, 0);
#pragma unroll 1
  for (int st = 0; st < 15; ++st) {
    bf16x8 av[6];
    {
      const size_t kchunk = (size_t)(half * 64 + st * 4 + w);
      const short* ap = Apack + kchunk * 3072 + (size_t)l * 8;
#pragma unroll
      for (int t = 0; t < 6; ++t) av[t] = *(const bf16x8*)(ap + t * 512);
    }
    __builtin_amdgcn_sched_barrier(0);   // A-loads stay BEFORE the DMAs
    stage(st + 1, (st + 1) & 1);
    __builtin_amdgcn_sched_barrier(0);
    asm volatile("s_waitcnt vmcnt(2)" ::: "memory");   // drains stage(st)+A(st)
    __builtin_amdgcn_sched_barrier(0);
    __builtin_amdgcn_s_barrier();        // all waves' stage(st) visible
    __builtin_amdgcn_sched_barrier(0);
    consume(st, av);
    __builtin_amdgcn_sched_barrier(0);
    __builtin_amdgcn_s_barrier();        // reads done before buf overwrite
    __builtin_amdgcn_sched_barrier(0);
  }
  {                                      // st = 15 peel
    bf16x8 av[6];
    const size_t kchunk = (size_t)(half * 64 + 15 * 4 + w);
    const short* ap = Apack + kchunk * 3072 + (size_t)l * 8;
#pragma unroll
    for (int t = 0; t < 6; ++t) av[t] = *(const bf16x8*)(ap + t * 512);
    __builtin_amdgcn_sched_barrier(0);
    asm volatile("s_waitcnt vmcnt(0)" ::: "memory");
    __builtin_amdgcn_sched_barrier(0);
    __builtin_amdgcn_s_barrier();
    __builtin_amdgcn_sched_barrier(0);
    consume(15, av);
  }
  __syncthreads();                       // full drain before smem reuse

  // partials: hp[w][16][100] in reused smem
  {
    float* hpw = smem + w * 1600;
#pragma unroll
    for (int t = 0; t < 6; ++t)
#pragma unroll
      for (int q = 0; q < 4; ++q)
        hpw[(lk * 4 + q) * 100 + t * 16 + lm] = acc[t][q];
  }
  __syncthreads();

  // reduce 4 wave-partials -> fp32 fragments -> hg[half][tile][kc][lane][8]
  if (tid < 192) {
    int r = tid / 12, c8 = tid % 12;     // row 0..15, col-group of 8
    const float* p = smem + r * 100 + c8 * 8;
    f32x4 s0 = *(const f32x4*)(p)        + *(const f32x4*)(p + 1600)
             + *(const f32x4*)(p + 3200) + *(const f32x4*)(p + 4800);
    f32x4 s1 = *(const f32x4*)(p + 4)    + *(const f32x4*)(p + 1604)
             + *(const f32x4*)(p + 3204) + *(const f32x4*)(p + 4804);
    float* dst = hg + ((size_t)half * 1024 + tile) * 1536
               + (size_t)((c8 >> 2) * 64 + (c8 & 3) * 16 + r) * 8;
    *(f32x4*)dst = s0;
    *(f32x4*)(dst + 4) = s1;
  }
}

// ---------------------------------------------------------------------------
// Stage 2 (r8-proven structure): B-fragments resident in registers, iterate
// over row-tiles; sums the 2 fp32 K-half partials before cvt. Swapped mfma
// operands -> one contiguous dwordx4 store per tile. ~42 us write floor.
// ---------------------------------------------------------------------------
__global__ __launch_bounds__(256, 6) void lora_stage2(
    const float* __restrict__ hg, const short* __restrict__ Bpack,
    float* __restrict__ out)
{
  const int bid = blockIdx.x;
  const int rs = bid >> 4;               // row-slab: tiles rs*8 .. +8
  const int cb = bid & 15;               // 256-col group
  const int tid = threadIdx.x;
  const int w = tid >> 6, l = tid & 63;
  const int lm = l & 15, lk = l >> 4;
  const int nt0 = cb * 16 + w * 4;       // wave's 4 n-tiles

  // persistent B fragments: 4 nt x 3 kc (48 VGPR)
  bf16x8 bf[4][3];
#pragma unroll
  for (int n = 0; n < 4; ++n)
#pragma unroll
    for (int kc = 0; kc < 3; ++kc)
      bf[n][kc] = *(const bf16x8*)(Bpack + ((size_t)(kc * 256 + nt0 + n)) * 512 + l * 8);

#pragma unroll 2
  for (int it = 0; it < 8; ++it) {
    const int tile = rs * 8 + it;
    const float* hp0 = hg + (size_t)tile * 1536 + (size_t)l * 8;
    const float* hp1 = hp0 + (size_t)1024 * 1536;
    bf16x8 hf[3];
#pragma unroll
    for (int kc = 0; kc < 3; ++kc) {
      f32x4 s0 = *(const f32x4*)(hp0 + kc * 512)
               + *(const f32x4*)(hp1 + kc * 512);
      f32x4 s1 = *(const f32x4*)(hp0 + kc * 512 + 4)
               + *(const f32x4*)(hp1 + kc * 512 + 4);
      bf16x8 o;
      o[0] = (short)f2bf(s0[0]); o[1] = (short)f2bf(s0[1]);
      o[2] = (short)f2bf(s0[2]); o[3] = (short)f2bf(s0[3]);
      o[4] = (short)f2bf(s1[0]); o[5] = (short)f2bf(s1[1]);
      o[6] = (short)f2bf(s1[2]); o[7] = (short)f2bf(s1[3]);
      hf[kc] = o;
    }
    float* orow = out + ((size_t)tile * 16 + lm) * 4096;
#pragma unroll
    for (int n = 0; n < 4; ++n) {
      f32x4 a = {0.f, 0.f, 0.f, 0.f};
      a = __builtin_amdgcn_mfma_f32_16x16x32_bf16(bf[n][0], hf[0], a, 0, 0, 0);
      a = __builtin_amdgcn_mfma_f32_16x16x32_bf16(bf[n][1], hf[1], a, 0, 0, 0);
      a = __builtin_amdgcn_mfma_f32_16x16x32_bf16(bf[n][2], hf[2], a, 0, 0, 0);
      *(f32x4*)(orow + (nt0 + n) * 16 + lk * 4) = a;
    }
  }
}

extern "C" void kernel_launch(void* const* d_in, const int* in_sizes, int n_in,
                              void* d_out, int out_size, void* d_ws, size_t ws_size,
                              hipStream_t stream) {
  const float* x  = (const float*)d_in[0];
  const float* Af = (const float*)d_in[1];
  const float* Bf = (const float*)d_in[2];
  const float* Am = (const float*)d_in[3];
  const float* Bm = (const float*)d_in[4];
  const float* As = (const float*)d_in[5];
  const float* Bs = (const float*)d_in[6];
  float* out = (float*)d_out;

  char* ws = (char*)d_ws;
  short* Apack = (short*)ws;                    // 786432 B
  short* Bpack = (short*)(ws + 786432);         // 786432 B
  float* hg    = (float*)(ws + 2 * 786432);     // 2*1024*1536*4 = 12582912 B

  hipLaunchKernelGGL(pack_AB, dim3(3072), dim3(256), 0, stream,
                     Af, Am, As, Bf, Bm, Bs, Apack, Bpack);
  hipLaunchKernelGGL(lora_stage1, dim3(2048), dim3(256), 0, stream, x, Apack, hg);
  hipLaunchKernelGGL(lora_stage2, dim3(2048), dim3(256), 0, stream, hg, Bpack, out);
}

// Round 11
// 228.760 us; speedup vs baseline: 1.1432x; 1.1432x over previous
//
#include <hip/hip_runtime.h>
#include <hip/hip_bf16.h>

typedef __attribute__((ext_vector_type(4))) float f32x4;
typedef __attribute__((ext_vector_type(8))) short bf16x8;

#define SBAR __builtin_amdgcn_sched_barrier(0)

// fp32 -> bf16 bits, round-to-nearest-even
__device__ __forceinline__ unsigned short f2bf(float f) {
  unsigned int u = __builtin_bit_cast(unsigned int, f);
  u += 0x7FFFu + ((u >> 16) & 1u);
  return (unsigned short)(u >> 16);
}

// ---------------------------------------------------------------------------
// Weight packing: fragment-order bf16 (same lane-mapping serves A-op & B-op).
// Apack[chunk][t][lane][j] = Acat[chunk*32 + (lane>>4)*8 + j][t*16 + (lane&15)]
// Bpack[kc][nt][lane][j]   = SCALE * Bcat[kc*32 + (lane>>4)*8 + j][nt*16 + (lane&15)]
// ---------------------------------------------------------------------------
__global__ __launch_bounds__(256) void pack_AB(
    const float* __restrict__ Af, const float* __restrict__ Am,
    const float* __restrict__ As, const float* __restrict__ Bf,
    const float* __restrict__ Bm, const float* __restrict__ Bs,
    short* __restrict__ Apack, short* __restrict__ Bpack)
{
  unsigned idx = blockIdx.x * 256u + threadIdx.x;     // < 786432
  if (idx < 393216u) {
    unsigned j = idx & 7u, lane = (idx >> 3) & 63u, rest = idx >> 9;
    unsigned t = rest % 6u, chunk = rest / 6u;
    unsigned k = chunk * 32u + ((lane >> 4) << 3) + j;
    unsigned c = t * 16u + (lane & 15u);
    float v;
    if (c < 32u)      v = Af[k * 32u + c];
    else if (c < 64u) v = Am[k * 32u + (c - 32u)];
    else              v = As[k * 32u + (c - 64u)];
    Apack[idx] = (short)f2bf(v);
  } else {
    unsigned i2 = idx - 393216u;
    unsigned j = i2 & 7u, lane = (i2 >> 3) & 63u, rest = i2 >> 9;
    unsigned nt = rest & 255u, kc = rest >> 8;
    unsigned k = kc * 32u + ((lane >> 4) << 3) + j;
    unsigned n = nt * 16u + (lane & 15u);
    float v;
    if (k < 32u)      v = Bf[k * 4096u + n];
    else if (k < 64u) v = Bm[(k - 32u) * 4096u + n];
    else              v = Bs[(k - 64u) * 4096u + n];
    Bpack[i2] = (short)f2bf(v * 0.03125f);            // fold SCALE = 1/32
  }
}

// ---------------------------------------------------------------------------
// Stage 1: hg bf16 fragments = x @ Apack. 1024 blocks (16 rows) x 4 waves.
// REGISTER staging (T14 split): per step of K=128, each wave issues 2 asm
// global_load_dwordx4 covering 4 rows x 512 B (purely linear source), holds
// them one step, then ds_write_b128 to XOR-swizzled LDS. Counted vmcnt(2)
// with A-loads hoisted into the drain shadow; ONE raw s_barrier per step.
// Single-variable test vs r7: LDS-DMA path -> register path.
// ---------------------------------------------------------------------------
__global__ __launch_bounds__(256, 4) void lora_stage1(
    const float* __restrict__ x, const short* __restrict__ Apack,
    short* __restrict__ hg)
{
  const int tile = blockIdx.x;           // 16-row tile
  const int tid = threadIdx.x;
  const int w = tid >> 6, l = tid & 63;
  const int lm = l & 15, lk = l >> 4;
  const size_t rowbase = (size_t)tile * 16;

  __shared__ __align__(16) float smem[6400];  // 16KB dbuf, 25.6KB reduce reuse

  f32x4 acc[6];
#pragma unroll
  for (int t = 0; t < 6; ++t) acc[t] = (f32x4){0.f, 0.f, 0.f, 0.f};

  // staging geometry: wave w owns rows w*4..+3; op i covers rows w*4+2i,+1.
  // lane l -> row rp = w*4 + 2i + (l>>5), source 16B-block b = l&31 (LINEAR),
  // LDS position = b ^ (rp&7)  (consume reads pos b0^(lm&7) -> source b0).
  const int rp0 = w * 4 + (l >> 5);
  const int rp1 = rp0 + 2;
  const int cfl = (l & 31) * 4;          // float offset within 512B row-chunk
  const float* g0 = x + (rowbase + rp0) * 4096 + cfl;
  const float* g1 = x + (rowbase + rp1) * 4096 + cfl;
  const int wp0 = rp0 * 128 + (((l & 31) ^ (rp0 & 7)) << 2);
  const int wp1 = rp1 * 128 + (((l & 31) ^ (rp1 & 7)) << 2);

#define XLOAD2(R0, R1, P0, P1)                                           \
  asm volatile("global_load_dwordx4 %0, %2, off\n\t"                     \
               "global_load_dwordx4 %1, %3, off"                         \
               : "=&v"(R0), "=&v"(R1) : "v"(P0), "v"(P1) : "memory")

  f32x4 xE0, xE1, xO0, xO1;

  auto consume = [&](int st, const bf16x8* av) {
    const float* rowp = smem + (st & 1) * 2048 + lm * 128;
    const int sw = lm & 7;
    const int b0 = w * 8 + lk * 2;       // wave w owns kchunk st*4+w
    f32x4 xa = *(const f32x4*)(rowp + ((b0 ^ sw) << 2));
    f32x4 xb = *(const f32x4*)(rowp + (((b0 + 1) ^ sw) << 2));
    bf16x8 xf;
    xf[0] = (short)f2bf(xa[0]); xf[1] = (short)f2bf(xa[1]);
    xf[2] = (short)f2bf(xa[2]); xf[3] = (short)f2bf(xa[3]);
    xf[4] = (short)f2bf(xb[0]); xf[5] = (short)f2bf(xb[1]);
    xf[6] = (short)f2bf(xb[2]); xf[7] = (short)f2bf(xb[3]);
#pragma unroll
    for (int t = 0; t < 6; ++t)
      acc[t] = __builtin_amdgcn_mfma_f32_16x16x32_bf16(xf, av[t], acc[t], 0, 0, 0);
  };

  // step body: A(st) -> x(st+1) -> vmcnt(2) -> ds_write cur -> lgkm -> bar -> consume
#define STEP(ST, CUR0, CUR1, NXT0, NXT1, LAST) do {                      \
    bf16x8 av[6];                                                        \
    const short* ap = Apack + (size_t)((ST) * 4 + w) * 3072 + (size_t)l * 8; \
    _Pragma("unroll")                                                    \
    for (int t = 0; t < 6; ++t) av[t] = *(const bf16x8*)(ap + t * 512);  \
    SBAR;                                                                \
    if (!(LAST)) { XLOAD2(NXT0, NXT1, g0 + ((ST) + 1) * 128, g1 + ((ST) + 1) * 128); } \
    SBAR;                                                                \
    if (LAST) asm volatile("s_waitcnt vmcnt(0)" ::: "memory");           \
    else      asm volatile("s_waitcnt vmcnt(2)" ::: "memory");           \
    SBAR;                                                                \
    { float* buf = smem + ((ST) & 1) * 2048;                             \
      *(f32x4*)(buf + wp0) = CUR0; *(f32x4*)(buf + wp1) = CUR1; }        \
    SBAR;                                                                \
    asm volatile("s_waitcnt lgkmcnt(0)" ::: "memory");                   \
    SBAR;                                                                \
    __builtin_amdgcn_s_barrier();                                        \
    SBAR;                                                                \
    consume((ST), av);                                                   \
    SBAR;                                                                \
  } while (0)

  XLOAD2(xE0, xE1, g0, g1);              // step 0 -> E
#pragma unroll 1
  for (int t2 = 0; t2 < 15; ++t2) {      // steps 0..29
    STEP(2 * t2,     xE0, xE1, xO0, xO1, 0);
    STEP(2 * t2 + 1, xO0, xO1, xE0, xE1, 0);
  }
  STEP(30, xE0, xE1, xO0, xO1, 0);
  STEP(31, xO0, xO1, xE0, xE1, 1);
  __syncthreads();                       // drain before smem reuse

  // partials: hp[w][16][100] in reused smem (r7/r8-proven epilogue)
  {
    float* hpw = smem + w * 1600;
#pragma unroll
    for (int t = 0; t < 6; ++t)
#pragma unroll
      for (int q = 0; q < 4; ++q)
        hpw[(lk * 4 + q) * 100 + t * 16 + lm] = acc[t][q];
  }
  __syncthreads();

  // reduce 4 wave-partials -> bf16 fragments -> hg[tile][kc][lane][8]
  if (tid < 192) {
    int r = tid / 12, c8 = tid % 12;     // row 0..15, col-group of 8
    const float* p = smem + r * 100 + c8 * 8;
    f32x4 s0 = *(const f32x4*)(p)        + *(const f32x4*)(p + 1600)
             + *(const f32x4*)(p + 3200) + *(const f32x4*)(p + 4800);
    f32x4 s1 = *(const f32x4*)(p + 4)    + *(const f32x4*)(p + 1604)
             + *(const f32x4*)(p + 3204) + *(const f32x4*)(p + 4804);
    bf16x8 o;
    o[0] = (short)f2bf(s0[0]); o[1] = (short)f2bf(s0[1]);
    o[2] = (short)f2bf(s0[2]); o[3] = (short)f2bf(s0[3]);
    o[4] = (short)f2bf(s1[0]); o[5] = (short)f2bf(s1[1]);
    o[6] = (short)f2bf(s1[2]); o[7] = (short)f2bf(s1[3]);
    *(bf16x8*)(hg + ((size_t)tile * 192 + (c8 >> 2) * 64 + (c8 & 3) * 16 + r) * 8) = o;
  }
}

// ---------------------------------------------------------------------------
// Stage 2 (r8-proven, reverted): B-fragments resident in registers, iterate
// over row-tiles; bf16 hg (3 MB, L2/L3-resident). Swapped mfma operands ->
// one contiguous dwordx4 store per tile. ~42 us HBM-write floor.
// ---------------------------------------------------------------------------
__global__ __launch_bounds__(256, 8) void lora_stage2(
    const short* __restrict__ hg, const short* __restrict__ Bpack,
    float* __restrict__ out)
{
  const int bid = blockIdx.x;
  const int rs = bid >> 4;               // row-slab: tiles rs*8 .. +8
  const int cb = bid & 15;               // 256-col group
  const int tid = threadIdx.x;
  const int w = tid >> 6, l = tid & 63;
  const int lm = l & 15, lk = l >> 4;
  const int nt0 = cb * 16 + w * 4;       // wave's 4 n-tiles

  // persistent B fragments: 4 nt x 3 kc (48 VGPR)
  bf16x8 bf[4][3];
#pragma unroll
  for (int n = 0; n < 4; ++n)
#pragma unroll
    for (int kc = 0; kc < 3; ++kc)
      bf[n][kc] = *(const bf16x8*)(Bpack + ((size_t)(kc * 256 + nt0 + n)) * 512 + l * 8);

#pragma unroll 2
  for (int it = 0; it < 8; ++it) {
    const int tile = rs * 8 + it;
    const short* hp = hg + (size_t)tile * 1536 + (size_t)l * 8;  // 192*8 shorts/tile
    bf16x8 hf0 = *(const bf16x8*)(hp);
    bf16x8 hf1 = *(const bf16x8*)(hp + 512);
    bf16x8 hf2 = *(const bf16x8*)(hp + 1024);
    float* orow = out + ((size_t)tile * 16 + lm) * 4096;
#pragma unroll
    for (int n = 0; n < 4; ++n) {
      f32x4 a = {0.f, 0.f, 0.f, 0.f};
      a = __builtin_amdgcn_mfma_f32_16x16x32_bf16(bf[n][0], hf0, a, 0, 0, 0);
      a = __builtin_amdgcn_mfma_f32_16x16x32_bf16(bf[n][1], hf1, a, 0, 0, 0);
      a = __builtin_amdgcn_mfma_f32_16x16x32_bf16(bf[n][2], hf2, a, 0, 0, 0);
      *(f32x4*)(orow + (nt0 + n) * 16 + lk * 4) = a;
    }
  }
}

extern "C" void kernel_launch(void* const* d_in, const int* in_sizes, int n_in,
                              void* d_out, int out_size, void* d_ws, size_t ws_size,
                              hipStream_t stream) {
  const float* x  = (const float*)d_in[0];
  const float* Af = (const float*)d_in[1];
  const float* Bf = (const float*)d_in[2];
  const float* Am = (const float*)d_in[3];
  const float* Bm = (const float*)d_in[4];
  const float* As = (const float*)d_in[5];
  const float* Bs = (const float*)d_in[6];
  float* out = (float*)d_out;

  char* ws = (char*)d_ws;
  short* Apack = (short*)ws;                    // 786432 B
  short* Bpack = (short*)(ws + 786432);         // 786432 B
  short* hg    = (short*)(ws + 2 * 786432);     // 1024*192*8*2 = 3145728 B

  hipLaunchKernelGGL(pack_AB, dim3(3072), dim3(256), 0, stream,
                     Af, Am, As, Bf, Bm, Bs, Apack, Bpack);
  hipLaunchKernelGGL(lora_stage1, dim3(1024), dim3(256), 0, stream, x, Apack, hg);
  hipLaunchKernelGGL(lora_stage2, dim3(2048), dim3(256), 0, stream, hg, Bpack, out);
}

// Round 12
// 160.705 us; speedup vs baseline: 1.6274x; 1.4235x over previous
//
#include <hip/hip_runtime.h>
#include <hip/hip_bf16.h>

typedef __attribute__((ext_vector_type(4))) float f32x4;
typedef __attribute__((ext_vector_type(8))) short bf16x8;

#define SBAR __builtin_amdgcn_sched_barrier(0)

// fp32 -> bf16 bits, round-to-nearest-even
__device__ __forceinline__ unsigned short f2bf(float f) {
  unsigned int u = __builtin_bit_cast(unsigned int, f);
  u += 0x7FFFu + ((u >> 16) & 1u);
  return (unsigned short)(u >> 16);
}

// async 16B global -> LDS (wave-uniform LDS base + lane*16 hardware layout)
__device__ __forceinline__ void async_ld16(const void* g, void* l) {
  __builtin_amdgcn_global_load_lds(
      (__attribute__((address_space(1))) void*)g,
      (__attribute__((address_space(3))) void*)l, 16, 0, 0);
}

// ---------------------------------------------------------------------------
// Weight packing: fragment-order bf16 (same lane-mapping serves A-op & B-op).
// Apack[chunk][t][lane][j] = Acat[chunk*32 + (lane>>4)*8 + j][t*16 + (lane&15)]
// Bpack[kc][nt][lane][j]   = SCALE * Bcat[kc*32 + (lane>>4)*8 + j][nt*16 + (lane&15)]
// ---------------------------------------------------------------------------
__global__ __launch_bounds__(256) void pack_AB(
    const float* __restrict__ Af, const float* __restrict__ Am,
    const float* __restrict__ As, const float* __restrict__ Bf,
    const float* __restrict__ Bm, const float* __restrict__ Bs,
    short* __restrict__ Apack, short* __restrict__ Bpack)
{
  unsigned idx = blockIdx.x * 256u + threadIdx.x;     // < 786432
  if (idx < 393216u) {
    unsigned j = idx & 7u, lane = (idx >> 3) & 63u, rest = idx >> 9;
    unsigned t = rest % 6u, chunk = rest / 6u;
    unsigned k = chunk * 32u + ((lane >> 4) << 3) + j;
    unsigned c = t * 16u + (lane & 15u);
    float v;
    if (c < 32u)      v = Af[k * 32u + c];
    else if (c < 64u) v = Am[k * 32u + (c - 32u)];
    else              v = As[k * 32u + (c - 64u)];
    Apack[idx] = (short)f2bf(v);
  } else {
    unsigned i2 = idx - 393216u;
    unsigned j = i2 & 7u, lane = (i2 >> 3) & 63u, rest = i2 >> 9;
    unsigned nt = rest & 255u, kc = rest >> 8;
    unsigned k = kc * 32u + ((lane >> 4) << 3) + j;
    unsigned n = nt * 16u + (lane & 15u);
    float v;
    if (k < 32u)      v = Bf[k * 4096u + n];
    else if (k < 64u) v = Bm[(k - 32u) * 4096u + n];
    else              v = Bs[(k - 64u) * 4096u + n];
    Bpack[i2] = (short)f2bf(v * 0.03125f);            // fold SCALE = 1/32
  }
}

// ---------------------------------------------------------------------------
// Stage 1 (r8 champion, verbatim): hg fragments = x @ Apack. 1024 blocks
// (16 rows) x 4 waves. Contiguous gload_lds staging, double buffer with RAW
// s_barrier + counted s_waitcnt vmcnt(4).
// ---------------------------------------------------------------------------
__global__ __launch_bounds__(256, 4) void lora_stage1(
    const float* __restrict__ x, const short* __restrict__ Apack,
    short* __restrict__ hg)
{
  const int rb  = blockIdx.x;            // 16-row tile
  const int tid = threadIdx.x;
  const int w = tid >> 6, l = tid & 63;
  const int lm = l & 15, lk = l >> 4;
  const size_t rowbase = (size_t)rb * 16;

  __shared__ __align__(16) float smem[8192];   // 32 KiB: xs dbuf -> hp reuse

  f32x4 acc[6];
#pragma unroll
  for (int t = 0; t < 6; ++t) acc[t] = (f32x4){0.f, 0.f, 0.f, 0.f};

  auto stage = [&](int s, int b) {
    float* base = smem + b * 4096;
    const float* gx = x + rowbase * 4096 + s * 256;
#pragma unroll
    for (int i = 0; i < 4; ++i) {
      int r = w * 4 + i;
      async_ld16(gx + (size_t)r * 4096 + ((l ^ (r & 7)) << 2), base + r * 256);
    }
  };

  auto consume = [&](int st) {
    const float* rowp = smem + (st & 1) * 4096 + lm * 256;
    const int sw = lm & 7;
#pragma unroll
    for (int p = 0; p < 2; ++p) {
      int ksub = w * 2 + p;
      int b0 = ksub * 8 + lk * 2;
      f32x4 xa = *(const f32x4*)(rowp + (((b0)     ^ sw) << 2));
      f32x4 xb = *(const f32x4*)(rowp + (((b0 + 1) ^ sw) << 2));
      bf16x8 xf;
      xf[0] = (short)f2bf(xa[0]); xf[1] = (short)f2bf(xa[1]);
      xf[2] = (short)f2bf(xa[2]); xf[3] = (short)f2bf(xa[3]);
      xf[4] = (short)f2bf(xb[0]); xf[5] = (short)f2bf(xb[1]);
      xf[6] = (short)f2bf(xb[2]); xf[7] = (short)f2bf(xb[3]);
      int kchunk = st * 8 + ksub;
#pragma unroll
      for (int t = 0; t < 6; ++t) {
        bf16x8 av = *(const bf16x8*)(Apack + ((size_t)kchunk * 6 + t) * 512 + l * 8);
        acc[t] = __builtin_amdgcn_mfma_f32_16x16x32_bf16(xf, av, acc[t], 0, 0, 0);
      }
    }
  };

  stage(0, 0);
#pragma unroll 1
  for (int st = 0; st < 15; ++st) {
    stage(st + 1, (st + 1) & 1);         // issue next step FIRST (FIFO shape)
    SBAR;
    asm volatile("s_waitcnt vmcnt(4)" ::: "memory");   // oldest step landed
    SBAR;
    __builtin_amdgcn_s_barrier();        // raw barrier: NO vmcnt(0) drain
    SBAR;
    consume(st);
    SBAR;
    __builtin_amdgcn_s_barrier();        // reads done before buf reuse
    SBAR;
  }
  asm volatile("s_waitcnt vmcnt(0)" ::: "memory");
  SBAR;
  __builtin_amdgcn_s_barrier();
  SBAR;
  consume(15);
  __syncthreads();                       // full drain before smem reuse

  // partials: hp[w][16][100] in reused smem
  {
    float* hpw = smem + w * 1600;
#pragma unroll
    for (int t = 0; t < 6; ++t)
#pragma unroll
      for (int q = 0; q < 4; ++q)
        hpw[(lk * 4 + q) * 100 + t * 16 + lm] = acc[t][q];
  }
  __syncthreads();

  // reduce 4 wave-partials -> bf16 fragments -> global hg[tile][kc][lane][8]
  if (tid < 192) {
    int r = tid / 12, c8 = tid % 12;     // row 0..15, col-group of 8
    const float* p = smem + r * 100 + c8 * 8;
    f32x4 s0 = *(const f32x4*)(p)        + *(const f32x4*)(p + 1600)
             + *(const f32x4*)(p + 3200) + *(const f32x4*)(p + 4800);
    f32x4 s1 = *(const f32x4*)(p + 4)    + *(const f32x4*)(p + 1604)
             + *(const f32x4*)(p + 3204) + *(const f32x4*)(p + 4804);
    bf16x8 o;
    o[0] = (short)f2bf(s0[0]); o[1] = (short)f2bf(s0[1]);
    o[2] = (short)f2bf(s0[2]); o[3] = (short)f2bf(s0[3]);
    o[4] = (short)f2bf(s1[0]); o[5] = (short)f2bf(s1[1]);
    o[6] = (short)f2bf(s1[2]); o[7] = (short)f2bf(s1[3]);
    *(bf16x8*)(hg + ((size_t)rb * 192 + (c8 >> 2) * 64 + (c8 & 3) * 16 + r) * 8) = o;
  }
}

// ---------------------------------------------------------------------------
// Stage 2 (NEW): same math as r8 (swapped-operand MFMA, B from L2), but D
// fragments go through an LDS transpose so every global store is 1 KB
// CONTIGUOUS within one out row (was 64 B scattered across 16 rows -> the
// 1.5x write amplification / 3.5 TB/s seen in r10's profile).
// 1024 blocks (16 rows x 4096 cols) x 4 waves; 16 panels of 256 cols.
// LDS [16][284] group-padded: pos(c) = c + (c>>5)*4 -> <=2-way banks on
// both write (scattered rows) and read (single row) sides.
// ---------------------------------------------------------------------------
__global__ __launch_bounds__(256, 4) void lora_stage2(
    const short* __restrict__ hg, const short* __restrict__ Bpack,
    float* __restrict__ out)
{
  const int tile = blockIdx.x;           // 16-row tile
  const int tid = threadIdx.x;
  const int w = tid >> 6, l = tid & 63;
  const int lm = l & 15, lk = l >> 4;

  __shared__ __align__(16) float trans[16 * 284];   // 17.75 KiB

  bf16x8 hf[3];
#pragma unroll
  for (int kc = 0; kc < 3; ++kc)
    hf[kc] = *(const bf16x8*)(hg + (size_t)tile * 1536 + kc * 512 + (size_t)l * 8);

  const int rc   = l * 4;                       // read col (floats)
  const int rpos = rc + ((rc >> 5) << 2);       // padded LDS position
  float* orow0 = out + (size_t)tile * 16 * 4096;

#pragma unroll 1
  for (int p = 0; p < 16; ++p) {
    // compute this panel's 4 n-tiles (wave w owns p*16 + w*4 .. +3)
    f32x4 a[4];
#pragma unroll
    for (int n = 0; n < 4; ++n) {
      const int nt = p * 16 + w * 4 + n;
      f32x4 acc = {0.f, 0.f, 0.f, 0.f};
#pragma unroll
      for (int kc = 0; kc < 3; ++kc) {
        bf16x8 bv = *(const bf16x8*)(Bpack + ((size_t)(kc * 256 + nt)) * 512 + l * 8);
        acc = __builtin_amdgcn_mfma_f32_16x16x32_bf16(bv, hf[kc], acc, 0, 0, 0);
      }
      a[n] = acc;
    }
    // D layout: row = lm, cols = (w*4+n)*16 + lk*4 + q  -> padded LDS
#pragma unroll
    for (int n = 0; n < 4; ++n) {
      int c = (w * 4 + n) * 16 + lk * 4;
      int pos = c + ((c >> 5) << 2);
      *(f32x4*)&trans[lm * 284 + pos] = a[n];
    }
    SBAR;
    asm volatile("s_waitcnt lgkmcnt(0)" ::: "memory");  // my writes visible
    SBAR;
    __builtin_amdgcn_s_barrier();                       // raw: no vmcnt drain
    SBAR;
    // read back row-linear; store 1 KB contiguous per instruction
#pragma unroll
    for (int rr = 0; rr < 4; ++rr) {
      int row = w * 4 + rr;
      f32x4 v = *(const f32x4*)&trans[row * 284 + rpos];
      *(f32x4*)(orow0 + (size_t)row * 4096 + p * 256 + rc) = v;
    }
    SBAR;
    __builtin_amdgcn_s_barrier();                       // reads done pre-reuse
    SBAR;
  }
}

extern "C" void kernel_launch(void* const* d_in, const int* in_sizes, int n_in,
                              void* d_out, int out_size, void* d_ws, size_t ws_size,
                              hipStream_t stream) {
  const float* x  = (const float*)d_in[0];
  const float* Af = (const float*)d_in[1];
  const float* Bf = (const float*)d_in[2];
  const float* Am = (const float*)d_in[3];
  const float* Bm = (const float*)d_in[4];
  const float* As = (const float*)d_in[5];
  const float* Bs = (const float*)d_in[6];
  float* out = (float*)d_out;

  char* ws = (char*)d_ws;
  short* Apack = (short*)ws;                    // 786432 B
  short* Bpack = (short*)(ws + 786432);         // 786432 B
  short* hg    = (short*)(ws + 2 * 786432);     // 1024*192*8*2 = 3145728 B

  hipLaunchKernelGGL(pack_AB, dim3(3072), dim3(256), 0, stream,
                     Af, Am, As, Bf, Bm, Bs, Apack, Bpack);
  hipLaunchKernelGGL(lora_stage1, dim3(1024), dim3(256), 0, stream, x, Apack, hg);
  hipLaunchKernelGGL(lora_stage2, dim3(1024), dim3(256), 0, stream, hg, Bpack, out);
}